// Round 2
// baseline (373.847 us; speedup 1.0000x reference)
//
#include <hip/hip_runtime.h>

// OnlineReweightingLoss: N=1048576, C=64, S=8.
// out = sum_k ( sum_{i in key k} per_sample_i ) / count_k
//     = sum_i per_sample_i / count[key_i]        (per-sample exact f32 div)
//
// R2 redesign: the old 3-kernel psum/pcnt scheme used 2 MB of workspace and a
// cross-slice reduce kernel. rocprof showed the timed region is dominated by
// 1 GiB workspace re-poison fills (~162 us each @6.6 TB/s), and the hist
// kernel itself is <160 us. New scheme:
//   Pass 1 (count):  read targets/subg (8 MB), 512-bin LDS histogram,
//                    global atomicAdd -> cnt[512] in ws (2 KB used).
//   Pass 2 (main):   read logits with PLAIN loads (no NT -> L2/L3 allowed),
//                    per-sample loss, exact IEEE f32 divide by count (same
//                    per-sample op as reference), per-thread accumulate,
//                    block reduce, one atomicAdd(out) per block.
// No psum/pcnt arrays, no reduce kernel.

#define NKEYS 512
typedef float v4f __attribute__((ext_vector_type(4)));

__device__ __forceinline__ float pick4(v4f v, int j) {
    float r = v.x;
    r = (j == 1) ? v.y : r;
    r = (j == 2) ? v.z : r;
    r = (j == 3) ? v.w : r;
    return r;
}

__device__ __forceinline__ float esum4(v4f v) {
    return __expf(v.x) + __expf(v.y) + __expf(v.z) + __expf(v.w);
}

// ---- Pass 1: global (target,subgroup) counts -> cnt[512] (pre-zeroed) ----
__global__ __launch_bounds__(256)
void orl_count_kernel(const int* __restrict__ targets,
                      const int* __restrict__ subg,
                      unsigned int* __restrict__ cnt,
                      int n) {
    __shared__ unsigned int lcnt[NKEYS];
    for (int i = threadIdx.x; i < NKEYS; i += 256) lcnt[i] = 0u;
    __syncthreads();

    const int tid = blockIdx.x * 256 + threadIdx.x;
    const int nthreads = gridDim.x * 256;
    const int n4 = n >> 2;
    for (int i4 = tid; i4 < n4; i4 += nthreads) {
        const int4 t4 = ((const int4*)targets)[i4];
        const int4 u4 = ((const int4*)subg)[i4];
        atomicAdd(&lcnt[t4.x * 8 + u4.x], 1u);
        atomicAdd(&lcnt[t4.y * 8 + u4.y], 1u);
        atomicAdd(&lcnt[t4.z * 8 + u4.z], 1u);
        atomicAdd(&lcnt[t4.w * 8 + u4.w], 1u);
    }
    for (int i = (n4 << 2) + tid; i < n; i += nthreads)
        atomicAdd(&lcnt[targets[i] * 8 + subg[i]], 1u);

    __syncthreads();
    for (int i = threadIdx.x; i < NKEYS; i += 256) {
        const unsigned int c = lcnt[i];
        if (c) atomicAdd(&cnt[i], c);
    }
}

// ---- Pass 2: fused loss + weight + global sum ----
__global__ __launch_bounds__(256, 6)
void orl_main_kernel(const float* __restrict__ logits,
                     const int* __restrict__ targets,
                     const int* __restrict__ subg,
                     const unsigned int* __restrict__ cnt,
                     float* __restrict__ out,
                     int n) {
    __shared__ float lcf[NKEYS];      // counts as exact floats (<= N < 2^24)
    for (int i = threadIdx.x; i < NKEYS; i += 256) lcf[i] = (float)cnt[i];
    __syncthreads();

    const int lane = threadIdx.x & 63;
    const int q    = lane & 15;        // float4 index within row
    const int g    = lane >> 4;        // 4-row group within wave's 16 rows
    const int wave = (blockIdx.x << 2) | (threadIdx.x >> 6);
    const int nwaves = gridDim.x << 2;

    float acc = 0.0f;
    int base = wave * 16;
    for (; base + 16 <= n; base += nwaves * 16) {
        const int r0 = base + g * 4;   // this lane-group's 4 contiguous rows
        const int4 t4 = *(const int4*)(targets + r0);
        const int4 u4 = *(const int4*)(subg + r0);
        // 4 independent dwordx4 loads, coalesced; PLAIN (cacheable) loads.
        const float* rowp = logits + (size_t)r0 * 64 + q * 4;
        const v4f v0 = *(const v4f*)(rowp);
        const v4f v1 = *(const v4f*)(rowp + 64);
        const v4f v2 = *(const v4f*)(rowp + 128);
        const v4f v3 = *(const v4f*)(rowp + 192);

        float s0 = esum4(v0), s1 = esum4(v1), s2 = esum4(v2), s3 = esum4(v3);
        // xor-reduce over the 16 q-lanes sharing each row
        #pragma unroll
        for (int m = 1; m < 16; m <<= 1) {
            s0 += __shfl_xor(s0, m, 16);
            s1 += __shfl_xor(s1, m, 16);
            s2 += __shfl_xor(s2, m, 16);
            s3 += __shfl_xor(s3, m, 16);
        }
        if ((t4.x >> 2) == q)
            acc += (__logf(s0) - pick4(v0, t4.x & 3)) / lcf[t4.x * 8 + u4.x];
        if ((t4.y >> 2) == q)
            acc += (__logf(s1) - pick4(v1, t4.y & 3)) / lcf[t4.y * 8 + u4.y];
        if ((t4.z >> 2) == q)
            acc += (__logf(s2) - pick4(v2, t4.z & 3)) / lcf[t4.z * 8 + u4.z];
        if ((t4.w >> 2) == q)
            acc += (__logf(s3) - pick4(v3, t4.w & 3)) / lcf[t4.w * 8 + u4.w];
    }
    // generic-n tail (not taken for N=1M with this grid)
    for (int o = 0; o < 4; ++o) {
        const int r = base + g * 4 + o;
        if (r < n) {
            const v4f v = *((const v4f*)(logits + (size_t)r * 64) + q);
            const int t = targets[r];
            float s = esum4(v);
            #pragma unroll
            for (int m = 1; m < 16; m <<= 1) s += __shfl_xor(s, m, 16);
            if ((t >> 2) == q)
                acc += (__logf(s) - pick4(v, t & 3)) / lcf[t * 8 + subg[r]];
        }
    }

    // wave reduce, then block reduce, one atomicAdd per block
    #pragma unroll
    for (int m = 1; m < 64; m <<= 1) acc += __shfl_xor(acc, m, 64);
    __shared__ float wsum[4];
    if (lane == 0) wsum[threadIdx.x >> 6] = acc;
    __syncthreads();
    if (threadIdx.x == 0)
        atomicAdd(out, wsum[0] + wsum[1] + wsum[2] + wsum[3]);
}

extern "C" void kernel_launch(void* const* d_in, const int* in_sizes, int n_in,
                              void* d_out, int out_size, void* d_ws, size_t ws_size,
                              hipStream_t stream) {
    const float* logits  = (const float*)d_in[0];
    const int*   targets = (const int*)d_in[1];
    const int*   subg    = (const int*)d_in[2];
    const int n = in_sizes[1];
    float* out = (float*)d_out;

    unsigned int* cnt = (unsigned int*)d_ws;   // 2 KB of workspace used

    hipMemsetAsync(out, 0, sizeof(float), stream);
    hipMemsetAsync(cnt, 0, NKEYS * sizeof(unsigned int), stream);
    orl_count_kernel<<<256, 256, 0, stream>>>(targets, subg, cnt, n);
    orl_main_kernel<<<2048, 256, 0, stream>>>(logits, targets, subg, cnt, out, n);
}